// Round 3
// baseline (4007.631 us; speedup 1.0000x reference)
//
#include <hip/hip_runtime.h>
#include <hip/hip_bf16.h>
#include <math.h>

// Problem constants
#define B_    4
#define S_    2048
#define D_    512
#define H_    8
#define DH_   64
#define E_    8
#define HID_  1365
#define HIDP_ 1408
#define CAP_  1024
#define TOK_  (B_*S_)
#define NASS_ (B_*2*S_)
#define RMAX_ (NASS_ + 8*128)
#define SUSP_CAP 1536
#define TAU 0.03f

typedef __attribute__((ext_vector_type(8))) short bf16x8;
typedef __attribute__((ext_vector_type(4))) float f32x4;
typedef __hip_bfloat16 bf16;

#define MFMA16(a, b, c) __builtin_amdgcn_mfma_f32_16x16x32_bf16(a, b, c, 0, 0, 0)

__device__ __forceinline__ void gload16(const void* g, void* l) {
  __builtin_amdgcn_global_load_lds(
      (const __attribute__((address_space(1))) unsigned int*)g,
      (__attribute__((address_space(3))) unsigned int*)l, 16, 0, 0);
}

__device__ __forceinline__ unsigned bf16pk(float a, float b) {
  unsigned ua = __float_as_uint(a); ua = (ua + 0x7FFF + ((ua >> 16) & 1)) >> 16;
  unsigned ub = __float_as_uint(b); ub = (ub + 0x7FFF + ((ub >> 16) & 1)) >> 16;
  return ua | (ub << 16);
}

__device__ __forceinline__ unsigned short bf16rne(float x, float& back) {
  unsigned u = __float_as_uint(x);
  unsigned r = (u + 0x7FFF + ((u >> 16) & 1)) >> 16;
  back = __uint_as_float(r << 16);
  return (unsigned short)r;
}

// ---------------------------------------------------------------------------
// fp32 -> bf16 elementwise
// ---------------------------------------------------------------------------
__global__ __launch_bounds__(256) void cvt_bf16(const float* __restrict__ in,
                                                bf16* __restrict__ out, int n) {
  int i = (blockIdx.x * 256 + threadIdx.x) * 4;
  if (i < n) {
    float4 v = *(const float4*)(in + i);
    uint2 pk; pk.x = bf16pk(v.x, v.y); pk.y = bf16pk(v.z, v.w);
    *(uint2*)((unsigned short*)out + i) = pk;
  }
}

// ---------------------------------------------------------------------------
// fp32 -> (hi, mid, lo) bf16 split (3x8-bit mantissa ~ fp32)
// ---------------------------------------------------------------------------
__global__ __launch_bounds__(256) void split3v(const float* __restrict__ in,
    unsigned short* __restrict__ ph, unsigned short* __restrict__ pm,
    unsigned short* __restrict__ pl, int n) {
  int i = (blockIdx.x * 256 + threadIdx.x) * 4;
  if (i >= n) return;
  float4 v = *(const float4*)(in + i);
  float a[4] = {v.x, v.y, v.z, v.w};
  ushort4 hh, mm, ll;
  unsigned short* hp = (unsigned short*)&hh;
  unsigned short* mp = (unsigned short*)&mm;
  unsigned short* lp = (unsigned short*)&ll;
#pragma unroll
  for (int j = 0; j < 4; j++) {
    float fh, fm, fl;
    hp[j] = bf16rne(a[j], fh);
    float r = a[j] - fh;
    mp[j] = bf16rne(r, fm);
    float r2 = r - fm;
    lp[j] = bf16rne(r2, fl);
  }
  *(ushort4*)(ph + i) = hh;
  *(ushort4*)(pm + i) = mm;
  *(ushort4*)(pl + i) = ll;
}

// ---------------------------------------------------------------------------
// W1 [e][512][1365] fp32 -> W1t [e][1408][512] bf16 (zero pad n>=1365)
// ---------------------------------------------------------------------------
__global__ __launch_bounds__(256) void transpose_w1(const float* __restrict__ W1,
                                                    bf16* __restrict__ W1t) {
  __shared__ float t[32][33];
  int e = blockIdx.z;
  int n0 = blockIdx.x * 32, d0 = blockIdx.y * 32;
  int tx = threadIdx.x & 31, ty = threadIdx.x >> 5;
  const float* in = W1 + (size_t)e * D_ * HID_;
  bf16* out = W1t + (size_t)e * HIDP_ * D_;
#pragma unroll
  for (int j = 0; j < 4; j++) {
    int d = d0 + ty + j * 8, n = n0 + tx;
    t[ty + j * 8][tx] = (n < HID_) ? in[(size_t)d * HID_ + n] : 0.f;
  }
  __syncthreads();
#pragma unroll
  for (int j = 0; j < 4; j++) {
    int n = n0 + ty + j * 8, d = d0 + tx;
    out[(size_t)n * D_ + d] = __float2bfloat16(t[tx][ty + j * 8]);
  }
}

// ---------------------------------------------------------------------------
// W2 [e][1365][512] fp32 -> W2t [e][512][1408] bf16 (zero pad k>=1365)
// ---------------------------------------------------------------------------
__global__ __launch_bounds__(256) void transpose_w2(const float* __restrict__ W2,
                                                    bf16* __restrict__ W2t) {
  __shared__ float t[32][33];
  int e = blockIdx.z;
  int n0 = blockIdx.x * 32, k0 = blockIdx.y * 32;
  int tx = threadIdx.x & 31, ty = threadIdx.x >> 5;
  const float* in = W2 + (size_t)e * HID_ * D_;
  bf16* out = W2t + (size_t)e * D_ * HIDP_;
#pragma unroll
  for (int j = 0; j < 4; j++) {
    int k = k0 + ty + j * 8;
    t[ty + j * 8][tx] = (k < HID_) ? in[(size_t)k * D_ + n0 + tx] : 0.f;
  }
  __syncthreads();
#pragma unroll
  for (int j = 0; j < 4; j++) {
    int n = n0 + ty + j * 8, k = k0 + tx;
    out[(size_t)n * HIDP_ + k] = __float2bfloat16(t[tx][ty + j * 8]);
  }
}

// ---------------------------------------------------------------------------
// v part of qkv [8192][1536] bf16 -> vT [b*8+h][64][2048] bf16
// ---------------------------------------------------------------------------
__global__ __launch_bounds__(256) void transpose_v(const bf16* __restrict__ qkv,
                                                   bf16* __restrict__ vT) {
  __shared__ bf16 t[32][33];
  int bh = blockIdx.z;
  int b = bh >> 3, h = bh & 7;
  int s0 = blockIdx.x * 32, d0 = blockIdx.y * 32;
  int tx = threadIdx.x & 31, ty = threadIdx.x >> 5;
  const bf16* in = qkv + (size_t)b * S_ * (3 * D_) + 2 * D_ + h * DH_;
#pragma unroll
  for (int j = 0; j < 4; j++)
    t[ty + j * 8][tx] = in[(size_t)(s0 + ty + j * 8) * (3 * D_) + d0 + tx];
  __syncthreads();
  bf16* out = vT + (size_t)bh * DH_ * S_;
#pragma unroll
  for (int j = 0; j < 4; j++)
    out[(size_t)(d0 + ty + j * 8) * S_ + s0 + tx] = t[tx][ty + j * 8];
}

// ---------------------------------------------------------------------------
// MFMA GEMM NT. 128x128 tile, BK=64, 256 thr (4 waves 2x2).
// MODE 0: QKV (bias, out bf16)   MODE 1: Wo (bias+resid, out fp32)
// MODE 2: FFN1 (bias, LeakyReLU, out bf16)   MODE 3: FFN2 (bias, out bf16)
// ---------------------------------------------------------------------------
template <int MODE>
__global__ __launch_bounds__(256) void gemm_mfma(
    const bf16* __restrict__ A, const bf16* __restrict__ Bt,
    const float* __restrict__ bias, const float* __restrict__ resid,
    void* __restrict__ Cout, int N, int K,
    const int* __restrict__ ebase, const int* __restrict__ ecnt) {
  __shared__ bf16 Al[128 * 64];
  __shared__ bf16 Bl[128 * 64];
  int tid = threadIdx.x;
  int w = tid >> 6, lane = tid & 63;
  int lg = lane >> 4, li = lane & 15;
  int e = 0;
  size_t arow0;
  if constexpr (MODE >= 2) {
    e = blockIdx.z;
    int r0 = blockIdx.y * 128;
    if (r0 >= ecnt[e]) return;
    arow0 = (size_t)(ebase[e] + r0);
  } else {
    arow0 = (size_t)blockIdx.y * 128;
  }
  int n0 = blockIdx.x * 128;
  const bf16* Bexp = Bt + (size_t)e * N * K;

  int rowA[4], scA[4];
#pragma unroll
  for (int j = 0; j < 4; j++) {
    int o = w * 4096 + j * 1024 + lane * 16;
    rowA[j] = o >> 7;
    scA[j] = ((o >> 4) & 7) ^ (rowA[j] & 7);
  }
  int wm = w >> 1, wn = w & 1;
  f32x4 acc[4][4] = {};

  for (int k0 = 0; k0 < K; k0 += 64) {
#pragma unroll
    for (int j = 0; j < 4; j++) {
      int o = w * 4096 + j * 1024 + lane * 16;
      gload16(A + (arow0 + rowA[j]) * (size_t)K + k0 + scA[j] * 8, (char*)Al + o);
      gload16(Bexp + (size_t)(n0 + rowA[j]) * K + k0 + scA[j] * 8, (char*)Bl + o);
    }
    __syncthreads();
#pragma unroll
    for (int ks = 0; ks < 2; ks++) {
      bf16x8 af[4], bfr[4];
#pragma unroll
      for (int mi = 0; mi < 4; mi++) {
        int row = wm * 64 + mi * 16 + li;
        int cb = (lg * 16 + ks * 64) ^ ((row & 7) << 4);
        af[mi] = *(const bf16x8*)((char*)Al + row * 128 + cb);
      }
#pragma unroll
      for (int ni = 0; ni < 4; ni++) {
        int row = wn * 64 + ni * 16 + li;
        int cb = (lg * 16 + ks * 64) ^ ((row & 7) << 4);
        bfr[ni] = *(const bf16x8*)((char*)Bl + row * 128 + cb);
      }
#pragma unroll
      for (int mi = 0; mi < 4; mi++)
#pragma unroll
        for (int ni = 0; ni < 4; ni++)
          acc[mi][ni] = MFMA16(af[mi], bfr[ni], acc[mi][ni]);
    }
    __syncthreads();
  }

#pragma unroll
  for (int mi = 0; mi < 4; mi++) {
#pragma unroll
    for (int ni = 0; ni < 4; ni++) {
#pragma unroll
      for (int r = 0; r < 4; r++) {
        size_t m = arow0 + wm * 64 + mi * 16 + lg * 4 + r;
        int c = n0 + wn * 64 + ni * 16 + li;
        float v = acc[mi][ni][r];
        if constexpr (MODE == 0) {
          v += bias[c];
          ((bf16*)Cout)[m * (size_t)N + c] = __float2bfloat16(v);
        } else if constexpr (MODE == 1) {
          v += bias[c] + resid[m * (size_t)N + c];
          ((float*)Cout)[m * (size_t)N + c] = v;
        } else if constexpr (MODE == 2) {
          if (c < HID_) {
            v += bias[e * HID_ + c];
            v = (v > 0.f) ? v : 0.01f * v;
            ((bf16*)Cout)[m * (size_t)HIDP_ + c] = __float2bfloat16(v);
          } else {
            ((bf16*)Cout)[m * (size_t)HIDP_ + c] = __float2bfloat16(0.f);
          }
        } else {
          v += bias[e * D_ + c];
          ((bf16*)Cout)[m * (size_t)N + c] = __float2bfloat16(v);
        }
      }
    }
  }
}

// ---------------------------------------------------------------------------
// Split-3 high-precision GEMM: C fp32 = A*Bt^T via 6 bf16 MFMA products.
// 128x128 tile, BK=32. Used for accurate K/V projection (routing path).
// ---------------------------------------------------------------------------
__global__ __launch_bounds__(256) void gemm_split3(
    const bf16* __restrict__ Ah, const bf16* __restrict__ Am, const bf16* __restrict__ Al_,
    const bf16* __restrict__ Bh, const bf16* __restrict__ Bm, const bf16* __restrict__ Bl_,
    const float* __restrict__ bias, float* __restrict__ C, int N, int K) {
  __shared__ bf16 Ls[6][128 * 32];
  const bf16* Ap[3] = {Ah, Am, Al_};
  const bf16* Bp[3] = {Bh, Bm, Bl_};
  int tid = threadIdx.x;
  int w = tid >> 6, lane = tid & 63;
  int lg = lane >> 4, li = lane & 15;
  size_t m0 = (size_t)blockIdx.y * 128;
  int n0 = blockIdx.x * 128;
  int wm = w >> 1, wn = w & 1;
  f32x4 acc[4][4] = {};

  for (int k0 = 0; k0 < K; k0 += 32) {
#pragma unroll
    for (int p = 0; p < 3; p++) {
#pragma unroll
      for (int j = 0; j < 2; j++) {
        int o = w * 2048 + j * 1024 + lane * 16;
        int row = o >> 6;
        int sc = ((o >> 4) & 3) ^ (row & 3);
        gload16(Ap[p] + (m0 + row) * (size_t)K + k0 + sc * 8, (char*)Ls[p] + o);
        gload16(Bp[p] + (size_t)(n0 + row) * K + k0 + sc * 8, (char*)Ls[3 + p] + o);
      }
    }
    __syncthreads();
    bf16x8 af[3][4], bfv[3][4];
#pragma unroll
    for (int p = 0; p < 3; p++) {
#pragma unroll
      for (int mi = 0; mi < 4; mi++) {
        int row = wm * 64 + mi * 16 + li;
        int cb = (lg * 16) ^ ((row & 3) << 4);
        af[p][mi] = *(const bf16x8*)((char*)Ls[p] + row * 64 + cb);
      }
#pragma unroll
      for (int ni = 0; ni < 4; ni++) {
        int row = wn * 64 + ni * 16 + li;
        int cb = (lg * 16) ^ ((row & 3) << 4);
        bfv[p][ni] = *(const bf16x8*)((char*)Ls[3 + p] + row * 64 + cb);
      }
    }
#pragma unroll
    for (int mi = 0; mi < 4; mi++)
#pragma unroll
      for (int ni = 0; ni < 4; ni++) {
        acc[mi][ni] = MFMA16(af[0][mi], bfv[0][ni], acc[mi][ni]);  // hh
        acc[mi][ni] = MFMA16(af[0][mi], bfv[1][ni], acc[mi][ni]);  // hm
        acc[mi][ni] = MFMA16(af[1][mi], bfv[0][ni], acc[mi][ni]);  // mh
        acc[mi][ni] = MFMA16(af[1][mi], bfv[1][ni], acc[mi][ni]);  // mm
        acc[mi][ni] = MFMA16(af[0][mi], bfv[2][ni], acc[mi][ni]);  // hl
        acc[mi][ni] = MFMA16(af[2][mi], bfv[0][ni], acc[mi][ni]);  // lh
      }
    __syncthreads();
  }
#pragma unroll
  for (int mi = 0; mi < 4; mi++)
#pragma unroll
    for (int ni = 0; ni < 4; ni++)
#pragma unroll
      for (int r = 0; r < 4; r++) {
        size_t m = m0 + wm * 64 + mi * 16 + lg * 4 + r;
        int c = n0 + wn * 64 + ni * 16 + li;
        C[m * (size_t)N + c] = acc[mi][ni][r] + bias[c];
      }
}

// ---------------------------------------------------------------------------
// MFMA flash attention (fast value path). 512 thr = 8 waves, 128 q rows.
// ---------------------------------------------------------------------------
__global__ __launch_bounds__(512) void attn_mfma(
    const bf16* __restrict__ qkv, const bf16* __restrict__ vT,
    bf16* __restrict__ attnb) {
  __shared__ bf16 Kl[128 * 64];
  __shared__ bf16 Vtl[64 * 128];
  __shared__ bf16 Pl[8][16 * 128];
  int b = blockIdx.z, h = blockIdx.y, q0 = blockIdx.x * 128;
  int tid = threadIdx.x, w = tid >> 6, lane = tid & 63;
  int lg = lane >> 4, qi = lane & 15;

  bf16x8 qf[2];
  const bf16* qrow =
      qkv + ((size_t)(b * S_ + q0 + w * 16 + qi)) * (3 * D_) + h * DH_ + lg * 8;
  qf[0] = *(const bf16x8*)(qrow);
  qf[1] = *(const bf16x8*)(qrow + 32);

  f32x4 oacc[4] = {};
  float mrun = -1e30f, lrun = 0.f;
  const bf16* Kbase = qkv + (size_t)b * S_ * (3 * D_) + D_ + h * DH_;
  const bf16* Vbase = vT + (size_t)(b * H_ + h) * DH_ * S_;
  char* pw = (char*)&Pl[w][0];

  for (int kt = 0; kt < S_ / 128; kt++) {
#pragma unroll
    for (int j = 0; j < 2; j++) {
      int o = w * 2048 + j * 1024 + lane * 16;
      int row = o >> 7;
      int sc = ((o >> 4) & 7) ^ (row & 7);
      gload16(Kbase + (size_t)(kt * 128 + row) * (3 * D_) + sc * 8, (char*)Kl + o);
    }
#pragma unroll
    for (int j = 0; j < 2; j++) {
      int o = w * 2048 + j * 1024 + lane * 16;
      int row = o >> 8;
      int sc = ((o >> 4) & 15) ^ (row & 7);
      gload16(Vbase + (size_t)row * S_ + kt * 128 + sc * 8, (char*)Vtl + o);
    }
    __syncthreads();

    f32x4 sacc[8];
#pragma unroll
    for (int nb = 0; nb < 8; nb++) { f32x4 z = {0.f, 0.f, 0.f, 0.f}; sacc[nb] = z; }
#pragma unroll
    for (int ks = 0; ks < 2; ks++) {
#pragma unroll
      for (int nb = 0; nb < 8; nb++) {
        int row = nb * 16 + qi;
        int cb = (lg * 16 + ks * 64) ^ ((row & 7) << 4);
        bf16x8 kf = *(const bf16x8*)((char*)Kl + row * 128 + cb);
        sacc[nb] = MFMA16(kf, qf[ks], sacc[nb]);
      }
    }
    float p[32];
    float tmax = -1e30f;
#pragma unroll
    for (int nb = 0; nb < 8; nb++)
#pragma unroll
      for (int r = 0; r < 4; r++) {
        float v = sacc[nb][r] * 0.125f;
        p[nb * 4 + r] = v;
        tmax = fmaxf(tmax, v);
      }
    tmax = fmaxf(tmax, __shfl_xor(tmax, 16));
    tmax = fmaxf(tmax, __shfl_xor(tmax, 32));
    float mnew = fmaxf(mrun, tmax);
    float fsc = __expf(mrun - mnew);
    float psum = 0.f;
#pragma unroll
    for (int i = 0; i < 32; i++) { p[i] = __expf(p[i] - mnew); psum += p[i]; }
    psum += __shfl_xor(psum, 16);
    psum += __shfl_xor(psum, 32);
    lrun = lrun * fsc + psum;
    mrun = mnew;
#pragma unroll
    for (int db = 0; db < 4; db++)
#pragma unroll
      for (int r = 0; r < 4; r++) oacc[db][r] *= fsc;
#pragma unroll
    for (int nb = 0; nb < 8; nb++)
#pragma unroll
      for (int rp = 0; rp < 2; rp++) {
        unsigned pk = bf16pk(p[nb * 4 + rp * 2], p[nb * 4 + rp * 2 + 1]);
        int key = 4 * lg + 2 * rp + 16 * nb;
        int addr = (qi * 256 + key * 2) ^ ((qi & 7) << 4);
        *(unsigned*)(pw + addr) = pk;
      }
#pragma unroll
    for (int ks2 = 0; ks2 < 4; ks2++) {
      int cbp = (qi * 256) + ((lg * 16 + ks2 * 64) ^ ((qi & 7) << 4));
      bf16x8 pf = *(const bf16x8*)(pw + cbp);
#pragma unroll
      for (int db = 0; db < 4; db++) {
        int row = db * 16 + qi;
        int cb = (lg * 16 + ks2 * 64) ^ ((row & 7) << 4);
        bf16x8 vf = *(const bf16x8*)((char*)Vtl + row * 256 + cb);
        oacc[db] = MFMA16(vf, pf, oacc[db]);
      }
    }
    __syncthreads();
  }

  float inv = 1.f / lrun;
  char* ow = (char*)Kl + w * 16 * 128;
#pragma unroll
  for (int db = 0; db < 4; db++)
#pragma unroll
    for (int rp = 0; rp < 2; rp++) {
      int d = db * 16 + lg * 4 + rp * 2;
      unsigned pk = bf16pk(oacc[db][rp * 2] * inv, oacc[db][rp * 2 + 1] * inv);
      int addr = (qi * 128 + d * 2) ^ ((qi & 7) << 4);
      *(unsigned*)(ow + addr) = pk;
    }
#pragma unroll
  for (int j = 0; j < 2; j++) {
    int o = j * 1024 + lane * 16;
    int q = o >> 7;
    int c16 = (o >> 4) & 7;
    int sc = c16 ^ (q & 7);
    bf16x8 vv = *(const bf16x8*)(ow + q * 128 + sc * 16);
    *(bf16x8*)(attnb + ((size_t)(b * S_ + q0 + w * 16 + q)) * D_ + h * DH_ + c16 * 8) = vv;
  }
}

// ---------------------------------------------------------------------------
// Gating: logits from o2 (fast), decisions, margins -> suspect lists, logbuf.
// ---------------------------------------------------------------------------
__global__ __launch_bounds__(256) void gating_kernel(
    const float* __restrict__ o2, const float* __restrict__ Wg,
    int* __restrict__ e1a, int* __restrict__ e2a,
    float* __restrict__ g1a, float* __restrict__ g2a, int* __restrict__ use2a,
    float* __restrict__ logbuf, int* __restrict__ suspcnt, int* __restrict__ suspb) {
  int tid = threadIdx.x;
  int tl = tid >> 3, j = tid & 7;
  int t = blockIdx.x * 32 + tl;
  const float* xr = o2 + (size_t)t * D_;
  float part[8] = {0, 0, 0, 0, 0, 0, 0, 0};
  for (int d = j; d < D_; d += 8) {
    float xv = xr[d];
    const float* wg = Wg + d * E_;
#pragma unroll
    for (int e = 0; e < 8; e++) part[e] += xv * wg[e];
  }
#pragma unroll
  for (int off = 1; off < 8; off <<= 1)
#pragma unroll
    for (int e = 0; e < 8; e++) part[e] += __shfl_xor(part[e], off);
  if (j == 0) {
#pragma unroll
    for (int e = 0; e < 8; e++) logbuf[(size_t)t * 8 + e] = part[e];
    float mx = part[0];
#pragma unroll
    for (int e = 1; e < 8; e++) mx = fmaxf(mx, part[e]);
    float p[8], se = 0.f;
#pragma unroll
    for (int e = 0; e < 8; e++) { p[e] = __expf(part[e] - mx); se += p[e]; }
    float inv = 1.f / se;
#pragma unroll
    for (int e = 0; e < 8; e++) p[e] *= inv;
    int a1 = 0; float m1 = p[0];
#pragma unroll
    for (int e = 1; e < 8; e++) if (p[e] > m1) { m1 = p[e]; a1 = e; }
    int a2 = -1; float m2 = -1.f;
#pragma unroll
    for (int e = 0; e < 8; e++) if (e != a1 && p[e] > m2) { m2 = p[e]; a2 = e; }
    float p3 = -1.f;
#pragma unroll
    for (int e = 0; e < 8; e++) if (e != a1 && e != a2 && p[e] > p3) p3 = p[e];
    e1a[t] = a1; e2a[t] = a2; g1a[t] = m1; g2a[t] = m2;
    use2a[t] = (m2 > 0.2f) ? 1 : 0;
    bool susp = (m1 - m2 < TAU) || (m2 - p3 < TAU) || (fabsf(m2 - 0.2f) < TAU);
    if (susp) {
      int b = t >> 11;
      int slot = atomicAdd(&suspcnt[b], 1);
      if (slot < SUSP_CAP) suspb[b * SUSP_CAP + slot] = t;
    }
  }
}

// ---------------------------------------------------------------------------
// fixup_q: accurate fp32 q rows for suspects (16 per pass).
// ---------------------------------------------------------------------------
__global__ __launch_bounds__(256) void fixup_q(
    const float* __restrict__ x, const float* __restrict__ Wqkv,
    const float* __restrict__ bqkv, const int* __restrict__ suspb,
    const int* __restrict__ suspcnt, float* __restrict__ qfix) {
  __shared__ float xs[16][512];
  int b = blockIdx.y;
  int cnt = min(suspcnt[b], SUSP_CAP);
  int tid = threadIdx.x;
  for (int c0 = blockIdx.x * 16; c0 < cnt; c0 += 32 * 16) {
    int ns = min(16, cnt - c0);
    __syncthreads();
    for (int i = tid; i < 16 * 512; i += 256) {
      int s2 = i >> 9, k = i & 511;
      xs[s2][k] = (s2 < ns) ? x[(size_t)suspb[b * SUSP_CAP + c0 + s2] * D_ + k] : 0.f;
    }
    __syncthreads();
#pragma unroll
    for (int half = 0; half < 2; half++) {
      int n = tid + half * 256;
      float acc[16];
#pragma unroll
      for (int s2 = 0; s2 < 16; s2++) acc[s2] = 0.f;
      const float4* wr = (const float4*)(Wqkv + (size_t)n * D_);
      for (int k4 = 0; k4 < 128; k4++) {
        float4 wv = wr[k4];
#pragma unroll
        for (int s2 = 0; s2 < 16; s2++)
          acc[s2] += wv.x * xs[s2][k4 * 4] + wv.y * xs[s2][k4 * 4 + 1] +
                     wv.z * xs[s2][k4 * 4 + 2] + wv.w * xs[s2][k4 * 4 + 3];
      }
      float bb = bqkv[n];
      for (int s2 = 0; s2 < ns; s2++)
        qfix[(size_t)(b * SUSP_CAP + c0 + s2) * D_ + n] = acc[s2] + bb;
    }
  }
}

// ---------------------------------------------------------------------------
// fixup_attn: exact fp32 flash attention for suspects vs accurate kv32.
// Block: 16 suspects x 1 head. lane16: keys l*8+j (scores), dims l*4+d (PV).
// ---------------------------------------------------------------------------
__global__ __launch_bounds__(256) void fixup_attn(
    const float* __restrict__ qfix, const float* __restrict__ kv32,
    const int* __restrict__ suspb, const int* __restrict__ suspcnt,
    float* __restrict__ oaccfix) {
  __shared__ float KT[64][130], VT[64][130], Pb[16][128], qs[16][64];
  int b = blockIdx.z, h = blockIdx.y;
  int cnt = min(suspcnt[b], SUSP_CAP);
  int tid = threadIdx.x;
  int ls = tid >> 4, l16 = tid & 15;
  for (int c = blockIdx.x; c * 16 < cnt; c += 32) {
    int ns = min(16, cnt - c * 16);
    __syncthreads();
    for (int i = tid; i < 16 * 64; i += 256) {
      int s2 = i >> 6, d = i & 63;
      qs[s2][d] = (s2 < ns) ? qfix[(size_t)(b * SUSP_CAP + c * 16 + s2) * D_ + h * 64 + d] : 0.f;
    }
    float mR = -1e30f, lR = 0.f;
    float o4[4] = {0.f, 0.f, 0.f, 0.f};
    for (int kt = 0; kt < 16; kt++) {
      __syncthreads();
      for (int i = tid; i < 128 * 64; i += 256) {
        int key = i >> 6, d = i & 63;
        const float* rp = kv32 + (size_t)(b * S_ + kt * 128 + key) * 1024 + h * 64 + d;
        KT[d][key] = rp[0];
        VT[d][key] = rp[512];
      }
      __syncthreads();
      float s8[8];
#pragma unroll
      for (int jj = 0; jj < 8; jj++) {
        int key = l16 * 8 + jj;
        float acc = 0.f;
        for (int d = 0; d < 64; d++) acc += qs[ls][d] * KT[d][key];
        s8[jj] = acc * 0.125f;
      }
      float tm = s8[0];
#pragma unroll
      for (int jj = 1; jj < 8; jj++) tm = fmaxf(tm, s8[jj]);
#pragma unroll
      for (int off = 1; off < 16; off <<= 1) tm = fmaxf(tm, __shfl_xor(tm, off));
      float mn = fmaxf(mR, tm);
      float fsc = __expf(mR - mn);
      float ts = 0.f;
#pragma unroll
      for (int jj = 0; jj < 8; jj++) {
        float pv = __expf(s8[jj] - mn);
        Pb[ls][l16 * 8 + jj] = pv;
        ts += pv;
      }
#pragma unroll
      for (int off = 1; off < 16; off <<= 1) ts += __shfl_xor(ts, off);
      lR = lR * fsc + ts;
      mR = mn;
#pragma unroll
      for (int dd = 0; dd < 4; dd++) o4[dd] *= fsc;
      int d0 = l16 * 4;
      for (int k = 0; k < 128; k++) {
        float pv = Pb[ls][k];
#pragma unroll
        for (int dd = 0; dd < 4; dd++) o4[dd] += pv * VT[d0 + dd][k];
      }
    }
    if (ls < ns) {
      float inv = 1.f / lR;
#pragma unroll
      for (int dd = 0; dd < 4; dd++)
        oaccfix[(size_t)(b * SUSP_CAP + c * 16 + ls) * D_ + h * 64 + l16 * 4 + dd] =
            o4[dd] * inv;
    }
  }
}

// ---------------------------------------------------------------------------
// fixup_final: Wo + residual + logits + decisions for suspects (fp32 exact).
// ---------------------------------------------------------------------------
__global__ __launch_bounds__(256) void fixup_final(
    const float* __restrict__ oaccfix, const float* __restrict__ Wo,
    const float* __restrict__ bo, const float* __restrict__ x,
    const float* __restrict__ Wg, const int* __restrict__ suspb,
    const int* __restrict__ suspcnt,
    int* __restrict__ e1a, int* __restrict__ e2a, float* __restrict__ g1a,
    float* __restrict__ g2a, int* __restrict__ use2a, float* __restrict__ logbuf) {
  __shared__ float os[16][512];
  __shared__ float o2s[16][512];
  __shared__ float lgs[16][8];
  int b = blockIdx.y;
  int cnt = min(suspcnt[b], SUSP_CAP);
  int tid = threadIdx.x;
  for (int c0 = blockIdx.x * 16; c0 < cnt; c0 += 32 * 16) {
    int ns = min(16, cnt - c0);
    __syncthreads();
    for (int i = tid; i < 16 * 512; i += 256) {
      int s2 = i >> 9, d = i & 511;
      os[s2][d] = (s2 < ns) ? oaccfix[(size_t)(b * SUSP_CAP + c0 + s2) * D_ + d] : 0.f;
    }
    __syncthreads();
#pragma unroll
    for (int half = 0; half < 2; half++) {
      int n = tid + half * 256;
      float acc[16];
#pragma unroll
      for (int s2 = 0; s2 < 16; s2++) acc[s2] = 0.f;
      const float4* wr = (const float4*)(Wo + (size_t)n * D_);
      for (int k4 = 0; k4 < 128; k4++) {
        float4 wv = wr[k4];
#pragma unroll
        for (int s2 = 0; s2 < 16; s2++)
          acc[s2] += wv.x * os[s2][k4 * 4] + wv.y * os[s2][k4 * 4 + 1] +
                     wv.z * os[s2][k4 * 4 + 2] + wv.w * os[s2][k4 * 4 + 3];
      }
      float bb = bo[n];
      for (int s2 = 0; s2 < ns; s2++) {
        int t = suspb[b * SUSP_CAP + c0 + s2];
        o2s[s2][n] = acc[s2] + bb + x[(size_t)t * D_ + n];
      }
    }
    __syncthreads();
    if (tid < 128) {
      int s2 = tid >> 3, e = tid & 7;
      float lg = 0.f;
      for (int d = 0; d < 512; d++) lg += o2s[s2][d] * Wg[d * 8 + e];
      lgs[s2][e] = lg;
    }
    __syncthreads();
    if (tid < ns) {
      int s2 = tid;
      int t = suspb[b * SUSP_CAP + c0 + s2];
      float lg[8];
#pragma unroll
      for (int e = 0; e < 8; e++) lg[e] = lgs[s2][e];
      float mx = lg[0];
#pragma unroll
      for (int e = 1; e < 8; e++) mx = fmaxf(mx, lg[e]);
      float p[8], se = 0.f;
#pragma unroll
      for (int e = 0; e < 8; e++) { p[e] = expf(lg[e] - mx); se += p[e]; }
      float inv = 1.f / se;
#pragma unroll
      for (int e = 0; e < 8; e++) p[e] *= inv;
      int a1 = 0; float m1 = p[0];
#pragma unroll
      for (int e = 1; e < 8; e++) if (p[e] > m1) { m1 = p[e]; a1 = e; }
      int a2 = -1; float m2 = -1.f;
#pragma unroll
      for (int e = 0; e < 8; e++) if (e != a1 && p[e] > m2) { m2 = p[e]; a2 = e; }
      e1a[t] = a1; e2a[t] = a2; g1a[t] = m1; g2a[t] = m2;
      use2a[t] = (m2 > 0.2f) ? 1 : 0;
#pragma unroll
      for (int e = 0; e < 8; e++) logbuf[(size_t)t * 8 + e] = lg[e];
    }
  }
}

// ---------------------------------------------------------------------------
// Aux-loss stats from final logits/argmax.
// ---------------------------------------------------------------------------
__global__ __launch_bounds__(256) void stats_kernel(
    const float* __restrict__ logbuf, const int* __restrict__ e1a,
    float* __restrict__ dacc) {
  int t = blockIdx.x * 256 + threadIdx.x;
  const float4* lp = (const float4*)(logbuf + (size_t)t * 8);
  float4 l0 = lp[0], l1 = lp[1];
  float lg[8] = {l0.x, l0.y, l0.z, l0.w, l1.x, l1.y, l1.z, l1.w};
  float mx = lg[0];
#pragma unroll
  for (int e = 1; e < 8; e++) mx = fmaxf(mx, lg[e]);
  float pr[8], se = 0.f;
#pragma unroll
  for (int e = 0; e < 8; e++) { pr[e] = __expf(lg[e] - mx); se += pr[e]; }
  float inv = 1.f / se;
#pragma unroll
  for (int e = 0; e < 8; e++) pr[e] *= inv;
  float lse = logf(se) + mx;
  float z = lse * lse;
#pragma unroll
  for (int off = 1; off < 64; off <<= 1) {
#pragma unroll
    for (int e = 0; e < 8; e++) pr[e] += __shfl_xor(pr[e], off);
    z += __shfl_xor(z, off);
  }
  int a1 = e1a[t];
  float dcnt[8];
#pragma unroll
  for (int e = 0; e < 8; e++)
    dcnt[e] = (float)__popcll(__ballot(a1 == e));
  if ((threadIdx.x & 63) == 0) {
#pragma unroll
    for (int e = 0; e < 8; e++) {
      atomicAdd(&dacc[e], dcnt[e]);
      atomicAdd(&dacc[8 + e], pr[e]);
    }
    atomicAdd(&dacc[16], z);
  }
}

// ---------------------------------------------------------------------------
// Capacity scan (exact cumsum order).
// ---------------------------------------------------------------------------
__global__ void scan_kernel(const int* __restrict__ e1a, const int* __restrict__ e2a,
                            const int* __restrict__ use2a,
                            int* __restrict__ posArr, int* __restrict__ kept_be) {
  int b = blockIdx.x;
  int lane = threadIdx.x;
  int cnt[8] = {0, 0, 0, 0, 0, 0, 0, 0};
  unsigned long long below = (1ull << lane) - 1ull;
  for (int it = 0; it < (2 * S_) / 64; it++) {
    int i = it * 64 + lane;
    int s = i & (S_ - 1);
    int t = b * S_ + s;
    int e, a;
    if (i < S_) { e = e1a[t]; a = 1; }
    else        { e = e2a[t]; a = use2a[t]; }
    int pos = -1;
#pragma unroll
    for (int ee = 0; ee < 8; ee++) {
      unsigned long long mask = __ballot(a && (e == ee));
      if (a && e == ee) pos = cnt[ee] + __popcll(mask & below);
      cnt[ee] += __popcll(mask);
    }
    posArr[b * (2 * S_) + i] = (a && pos < CAP_) ? pos : -1;
  }
  if (lane == 0)
    for (int ee = 0; ee < 8; ee++) kept_be[b * 8 + ee] = min(cnt[ee], CAP_);
}

// ---------------------------------------------------------------------------
// Meta: 128-aligned per-expert bases + aux-loss scalars.
// ---------------------------------------------------------------------------
__global__ void finalize_meta(const int* __restrict__ kept_be,
                              int* __restrict__ ebase, int* __restrict__ bbase,
                              int* __restrict__ ecnt,
                              const float* __restrict__ dacc, float* __restrict__ outs) {
  if (threadIdx.x == 0 && blockIdx.x == 0) {
    int base = 0;
    for (int e = 0; e < 8; e++) {
      int tot = 0;
      for (int b = 0; b < 4; b++) { bbase[b * 8 + e] = tot; tot += kept_be[b * 8 + e]; }
      ecnt[e] = tot;
      ebase[e] = base;
      base += (tot + 127) & ~127;
    }
    float bal = 0.f;
    for (int e = 0; e < 8; e++) bal += (dacc[e] / (float)TOK_) * (dacc[8 + e] / (float)TOK_);
    bal *= (float)E_;
    float z = dacc[16] / (float)TOK_;
    outs[0] = 0.01f * bal + 0.001f * z;
    outs[1] = bal;
    outs[2] = z;
  }
}

// ---------------------------------------------------------------------------
// Scatter: compacted row lists + per-token combine info.
// ---------------------------------------------------------------------------
__global__ __launch_bounds__(256) void scatter_kernel(
    const int* __restrict__ posArr, const int* __restrict__ e1a, const int* __restrict__ e2a,
    const float* __restrict__ g1a, const float* __restrict__ g2a,
    const int* __restrict__ ebase, const int* __restrict__ bbase,
    int* __restrict__ rowtok, int* __restrict__ rowexp,
    int* __restrict__ tokidx, float* __restrict__ tokw) {
  int gi = blockIdx.x * 256 + threadIdx.x;
  int b = gi >> 12, i = gi & 4095;
  int k = i >> 11, s = i & (S_ - 1);
  int t = b * S_ + s;
  int pos = posArr[gi];
  int idx = -1; float w = 0.f;
  if (pos >= 0) {
    int e = k ? e2a[t] : e1a[t];
    idx = ebase[e] + bbase[b * 8 + e] + pos;
    rowtok[idx] = t;
    rowexp[idx] = e;
    w = k ? g2a[t] : g1a[t];
  }
  tokidx[k * TOK_ + t] = idx;
  tokw[k * TOK_ + t] = w;
}

// ---------------------------------------------------------------------------
// LayerNorm per compacted row -> bf16.
// ---------------------------------------------------------------------------
__global__ __launch_bounds__(256) void ln_kernel(
    const float* __restrict__ o2, const int* __restrict__ rowtok,
    const int* __restrict__ rowexp, const float* __restrict__ ln_g,
    const float* __restrict__ ln_b, bf16* __restrict__ xn) {
  int row = blockIdx.x * 4 + (threadIdx.x >> 6);
  int lane = threadIdx.x & 63;
  int tok = rowtok[row];
  if (tok < 0) return;
  int e = rowexp[row];
  const float* xr = o2 + (size_t)tok * D_;
  float v[8], sum = 0.f, sq = 0.f;
#pragma unroll
  for (int j = 0; j < 8; j++) { v[j] = xr[lane * 8 + j]; sum += v[j]; sq += v[j] * v[j]; }
#pragma unroll
  for (int off = 1; off < 64; off <<= 1) { sum += __shfl_xor(sum, off); sq += __shfl_xor(sq, off); }
  float mu = sum / (float)D_;
  float var = sq / (float)D_ - mu * mu;
  float inv = rsqrtf(var + 1e-5f);
  bf16* xo = xn + (size_t)row * D_;
#pragma unroll
  for (int j = 0; j < 8; j++) {
    int d = lane * 8 + j;
    xo[d] = __float2bfloat16((v[j] - mu) * inv * ln_g[e * D_ + d] + ln_b[e * D_ + d]);
  }
}

// ---------------------------------------------------------------------------
// Combine: out = o2 + w1*y[idx1] + w2*y[idx2]   (y is bf16)
// ---------------------------------------------------------------------------
__global__ __launch_bounds__(256) void combine_kernel(
    const float* __restrict__ o2, const bf16* __restrict__ y,
    const int* __restrict__ tokidx, const float* __restrict__ tokw,
    float* __restrict__ out) {
  size_t gi = (size_t)blockIdx.x * 256 + threadIdx.x;
  int t = (int)(gi >> 9);
  int d = (int)(gi & (D_ - 1));
  float v = o2[gi];
  int i1 = tokidx[t], i2 = tokidx[TOK_ + t];
  if (i1 >= 0) v += tokw[t] * __bfloat162float(y[(size_t)i1 * D_ + d]);
  if (i2 >= 0) v += tokw[TOK_ + t] * __bfloat162float(y[(size_t)i2 * D_ + d]);
  out[gi] = v;
}

// ---------------------------------------------------------------------------
extern "C" void kernel_launch(void* const* d_in, const int* in_sizes, int n_in,
                              void* d_out, int out_size, void* d_ws, size_t ws_size,
                              hipStream_t stream) {
  const float* x    = (const float*)d_in[0];
  const float* Wqkv = (const float*)d_in[1];
  const float* bqkv = (const float*)d_in[2];
  const float* Wo   = (const float*)d_in[3];
  const float* bo   = (const float*)d_in[4];
  const float* Wg   = (const float*)d_in[5];
  const float* ln_g = (const float*)d_in[6];
  const float* ln_b = (const float*)d_in[7];
  const float* W1   = (const float*)d_in[8];
  const float* b1   = (const float*)d_in[9];
  const float* W2   = (const float*)d_in[10];
  const float* b2   = (const float*)d_in[11];
  float* out = (float*)d_out;

  char* ws = (char*)d_ws;
  size_t off = 0;
  auto alloc = [&](size_t bytes) -> void* {
    void* p = ws + off;
    off = (off + bytes + 255) & ~(size_t)255;
    return p;
  };
  bf16* qkv    = (bf16*)alloc((size_t)TOK_ * 3 * D_ * 2);
  float* kv32  = (float*)alloc((size_t)TOK_ * 1024 * 4);
  bf16* vT     = (bf16*)alloc((size_t)B_ * H_ * DH_ * S_ * 2);
  bf16* attnb  = (bf16*)alloc((size_t)TOK_ * D_ * 2);
  float* o2    = (float*)alloc((size_t)TOK_ * D_ * 4);
  bf16* xh     = (bf16*)alloc((size_t)TOK_ * D_ * 2);
  bf16* xm     = (bf16*)alloc((size_t)TOK_ * D_ * 2);
  bf16* xl     = (bf16*)alloc((size_t)TOK_ * D_ * 2);
  bf16* Wqkvb  = (bf16*)alloc((size_t)3 * D_ * D_ * 2);
  bf16* Wkvh   = (bf16*)alloc((size_t)1024 * D_ * 2);
  bf16* Wkvm   = (bf16*)alloc((size_t)1024 * D_ * 2);
  bf16* Wkvl   = (bf16*)alloc((size_t)1024 * D_ * 2);
  bf16* Wob    = (bf16*)alloc((size_t)D_ * D_ * 2);
  bf16* W1t    = (bf16*)alloc((size_t)E_ * HIDP_ * D_ * 2);
  bf16* W2t    = (bf16*)alloc((size_t)E_ * D_ * HIDP_ * 2);
  bf16* xn     = (bf16*)alloc((size_t)RMAX_ * D_ * 2);
  bf16* hbuf   = (bf16*)alloc((size_t)RMAX_ * HIDP_ * 2);
  bf16* ybuf   = (bf16*)alloc((size_t)RMAX_ * D_ * 2);
  float* logbuf = (float*)alloc((size_t)TOK_ * 8 * 4);
  float* qfix   = (float*)alloc((size_t)B_ * SUSP_CAP * D_ * 4);
  float* oaccfix= (float*)alloc((size_t)B_ * SUSP_CAP * D_ * 4);
  int*   suspb  = (int*)alloc(B_ * SUSP_CAP * 4);
  int*   suspcnt= (int*)alloc(16 * 4);
  int*   e1a    = (int*)alloc(TOK_ * 4);
  int*   e2a    = (int*)alloc(TOK_ * 4);
  int*   use2a  = (int*)alloc(TOK_ * 4);
  float* g1a    = (float*)alloc(TOK_ * 4);
  float* g2a    = (float*)alloc(TOK_ * 4);
  int*   posArr  = (int*)alloc(NASS_ * 4);
  int*   kept_be = (int*)alloc(32 * 4);
  int*   ebase   = (int*)alloc(8 * 4);
  int*   bbase   = (int*)alloc(32 * 4);
  int*   ecnt    = (int*)alloc(8 * 4);
  int*   rowtok  = (int*)alloc(RMAX_ * 4);
  int*   rowexp  = (int*)alloc(RMAX_ * 4);
  int*   tokidx  = (int*)alloc(NASS_ * 4);
  float* tokw    = (float*)alloc(NASS_ * 4);
  float* dacc    = (float*)alloc(32 * 4);

  hipMemsetAsync(dacc, 0, 32 * 4, stream);
  hipMemsetAsync(suspcnt, 0, 16 * 4, stream);
  hipMemsetAsync(rowtok, 0xFF, RMAX_ * 4, stream);

  // conversions / splits
  split3v<<<TOK_ * D_ / 4 / 256, 256, 0, stream>>>(x, (unsigned short*)xh,
                                                   (unsigned short*)xm,
                                                   (unsigned short*)xl, TOK_ * D_);
  split3v<<<1024 * D_ / 4 / 256, 256, 0, stream>>>(Wqkv + 512 * D_,
                                                   (unsigned short*)Wkvh,
                                                   (unsigned short*)Wkvm,
                                                   (unsigned short*)Wkvl, 1024 * D_);
  cvt_bf16<<<3 * D_ * D_ / 4 / 256, 256, 0, stream>>>(Wqkv, Wqkvb, 3 * D_ * D_);
  cvt_bf16<<<D_ * D_ / 4 / 256, 256, 0, stream>>>(Wo, Wob, D_ * D_);
  transpose_w1<<<dim3(44, 16, 8), 256, 0, stream>>>(W1, W1t);
  transpose_w2<<<dim3(16, 44, 8), 256, 0, stream>>>(W2, W2t);

  // fast QKV (bf16) + accurate KV (fp32, split-3)
  gemm_mfma<0><<<dim3(12, 64), 256, 0, stream>>>(xh, Wqkvb, bqkv, nullptr, qkv,
                                                 3 * D_, D_, nullptr, nullptr);
  gemm_split3<<<dim3(8, 64), 256, 0, stream>>>(xh, xm, xl, Wkvh, Wkvm, Wkvl,
                                               bqkv + 512, kv32, 1024, D_);
  transpose_v<<<dim3(64, 2, 32), 256, 0, stream>>>(qkv, vT);
  attn_mfma<<<dim3(S_ / 128, H_, B_), 512, 0, stream>>>(qkv, vT, attnb);
  gemm_mfma<1><<<dim3(4, 64), 256, 0, stream>>>(attnb, Wob, bo, x, o2,
                                                D_, D_, nullptr, nullptr);
  // gating + routing fixup
  gating_kernel<<<TOK_ / 32, 256, 0, stream>>>(o2, Wg, e1a, e2a, g1a, g2a, use2a,
                                               logbuf, suspcnt, suspb);
  fixup_q<<<dim3(32, B_), 256, 0, stream>>>(x, Wqkv, bqkv, suspb, suspcnt, qfix);
  fixup_attn<<<dim3(32, H_, B_), 256, 0, stream>>>(qfix, kv32, suspb, suspcnt, oaccfix);
  fixup_final<<<dim3(32, B_), 256, 0, stream>>>(oaccfix, Wo, bo, x, Wg, suspb, suspcnt,
                                                e1a, e2a, g1a, g2a, use2a, logbuf);
  stats_kernel<<<TOK_ / 256, 256, 0, stream>>>(logbuf, e1a, dacc);
  // dispatch
  scan_kernel<<<B_, 64, 0, stream>>>(e1a, e2a, use2a, posArr, kept_be);
  finalize_meta<<<1, 64, 0, stream>>>(kept_be, ebase, bbase, ecnt, dacc,
                                      out + (size_t)TOK_ * D_);
  scatter_kernel<<<NASS_ / 256, 256, 0, stream>>>(posArr, e1a, e2a, g1a, g2a,
                                                  ebase, bbase, rowtok, rowexp,
                                                  tokidx, tokw);
  ln_kernel<<<RMAX_ / 4, 256, 0, stream>>>(o2, rowtok, rowexp, ln_g, ln_b, xn);
  gemm_mfma<2><<<dim3(HIDP_ / 128, 32, E_), 256, 0, stream>>>(xn, W1t, b1, nullptr, hbuf,
                                                              HIDP_, D_, ebase, ecnt);
  gemm_mfma<3><<<dim3(D_ / 128, 32, E_), 256, 0, stream>>>(hbuf, W2t, b2, nullptr, ybuf,
                                                           D_, HIDP_, ebase, ecnt);
  combine_kernel<<<(TOK_ * D_) / 256, 256, 0, stream>>>(o2, ybuf, tokidx, tokw, out);
}

// Round 4
// 606.147 us; speedup vs baseline: 6.6116x; 6.6116x over previous
//
#include <hip/hip_runtime.h>
#include <hip/hip_bf16.h>
#include <math.h>

// Problem constants
#define B_    4
#define S_    2048
#define D_    512
#define H_    8
#define DH_   64
#define E_    8
#define HID_  1365
#define HIDP_ 1408
#define CAP_  1024
#define TOK_  (B_*S_)
#define NASS_ (B_*2*S_)
#define RMAX_ (NASS_ + 8*128)

typedef __attribute__((ext_vector_type(8))) short bf16x8;
typedef __attribute__((ext_vector_type(4))) float f32x4;
typedef __hip_bfloat16 bf16;

#define MFMA16(a, b, c) __builtin_amdgcn_mfma_f32_16x16x32_bf16(a, b, c, 0, 0, 0)

__device__ __forceinline__ void gload16(const void* g, void* l) {
  __builtin_amdgcn_global_load_lds(
      (const __attribute__((address_space(1))) unsigned int*)g,
      (__attribute__((address_space(3))) unsigned int*)l, 16, 0, 0);
}

__device__ __forceinline__ unsigned bf16pk(float a, float b) {
  unsigned ua = __float_as_uint(a); ua = (ua + 0x7FFF + ((ua >> 16) & 1)) >> 16;
  unsigned ub = __float_as_uint(b); ub = (ub + 0x7FFF + ((ub >> 16) & 1)) >> 16;
  return ua | (ub << 16);
}

__device__ __forceinline__ unsigned short bf16rne(float x, float& back) {
  unsigned u = __float_as_uint(x);
  unsigned r = (u + 0x7FFF + ((u >> 16) & 1)) >> 16;
  back = __uint_as_float(r << 16);
  return (unsigned short)r;
}

// ---------------------------------------------------------------------------
// fp32 -> bf16 elementwise
// ---------------------------------------------------------------------------
__global__ __launch_bounds__(256) void cvt_bf16(const float* __restrict__ in,
                                                bf16* __restrict__ out, int n) {
  int i = (blockIdx.x * 256 + threadIdx.x) * 4;
  if (i < n) {
    float4 v = *(const float4*)(in + i);
    uint2 pk; pk.x = bf16pk(v.x, v.y); pk.y = bf16pk(v.z, v.w);
    *(uint2*)((unsigned short*)out + i) = pk;
  }
}

// ---------------------------------------------------------------------------
// fp32 -> (hi, mid, lo) bf16 split
// ---------------------------------------------------------------------------
__global__ __launch_bounds__(256) void split3v(const float* __restrict__ in,
    unsigned short* __restrict__ ph, unsigned short* __restrict__ pm,
    unsigned short* __restrict__ pl, int n) {
  int i = (blockIdx.x * 256 + threadIdx.x) * 4;
  if (i >= n) return;
  float4 v = *(const float4*)(in + i);
  float a[4] = {v.x, v.y, v.z, v.w};
  ushort4 hh, mm, ll;
  unsigned short* hp = (unsigned short*)&hh;
  unsigned short* mp = (unsigned short*)&mm;
  unsigned short* lp = (unsigned short*)&ll;
#pragma unroll
  for (int j = 0; j < 4; j++) {
    float fh, fm, fl;
    hp[j] = bf16rne(a[j], fh);
    float r = a[j] - fh;
    mp[j] = bf16rne(r, fm);
    float r2 = r - fm;
    lp[j] = bf16rne(r2, fl);
  }
  *(ushort4*)(ph + i) = hh;
  *(ushort4*)(pm + i) = mm;
  *(ushort4*)(pl + i) = ll;
}

// ---------------------------------------------------------------------------
// W1 [e][512][1365] fp32 -> W1t [e][1408][512] bf16 (zero pad)
// ---------------------------------------------------------------------------
__global__ __launch_bounds__(256) void transpose_w1(const float* __restrict__ W1,
                                                    bf16* __restrict__ W1t) {
  __shared__ float t[32][33];
  int e = blockIdx.z;
  int n0 = blockIdx.x * 32, d0 = blockIdx.y * 32;
  int tx = threadIdx.x & 31, ty = threadIdx.x >> 5;
  const float* in = W1 + (size_t)e * D_ * HID_;
  bf16* out = W1t + (size_t)e * HIDP_ * D_;
#pragma unroll
  for (int j = 0; j < 4; j++) {
    int d = d0 + ty + j * 8, n = n0 + tx;
    t[ty + j * 8][tx] = (n < HID_) ? in[(size_t)d * HID_ + n] : 0.f;
  }
  __syncthreads();
#pragma unroll
  for (int j = 0; j < 4; j++) {
    int n = n0 + ty + j * 8, d = d0 + tx;
    out[(size_t)n * D_ + d] = __float2bfloat16(t[tx][ty + j * 8]);
  }
}

// ---------------------------------------------------------------------------
// W2 [e][1365][512] fp32 -> W2t [e][512][1408] bf16 (zero pad)
// ---------------------------------------------------------------------------
__global__ __launch_bounds__(256) void transpose_w2(const float* __restrict__ W2,
                                                    bf16* __restrict__ W2t) {
  __shared__ float t[32][33];
  int e = blockIdx.z;
  int n0 = blockIdx.x * 32, k0 = blockIdx.y * 32;
  int tx = threadIdx.x & 31, ty = threadIdx.x >> 5;
  const float* in = W2 + (size_t)e * HID_ * D_;
  bf16* out = W2t + (size_t)e * D_ * HIDP_;
#pragma unroll
  for (int j = 0; j < 4; j++) {
    int k = k0 + ty + j * 8;
    t[ty + j * 8][tx] = (k < HID_) ? in[(size_t)k * D_ + n0 + tx] : 0.f;
  }
  __syncthreads();
#pragma unroll
  for (int j = 0; j < 4; j++) {
    int n = n0 + ty + j * 8, k = k0 + tx;
    out[(size_t)n * HIDP_ + k] = __float2bfloat16(t[tx][ty + j * 8]);
  }
}

// ---------------------------------------------------------------------------
// v part of qkvb [8192][1536] bf16 -> vT [b*8+h][64][2048] bf16
// ---------------------------------------------------------------------------
__global__ __launch_bounds__(256) void transpose_v(const bf16* __restrict__ qkv,
                                                   bf16* __restrict__ vT) {
  __shared__ bf16 t[32][33];
  int bh = blockIdx.z;
  int b = bh >> 3, h = bh & 7;
  int s0 = blockIdx.x * 32, d0 = blockIdx.y * 32;
  int tx = threadIdx.x & 31, ty = threadIdx.x >> 5;
  const bf16* in = qkv + (size_t)b * S_ * (3 * D_) + 2 * D_ + h * DH_;
#pragma unroll
  for (int j = 0; j < 4; j++)
    t[ty + j * 8][tx] = in[(size_t)(s0 + ty + j * 8) * (3 * D_) + d0 + tx];
  __syncthreads();
  bf16* out = vT + (size_t)bh * DH_ * S_;
#pragma unroll
  for (int j = 0; j < 4; j++)
    out[(size_t)(d0 + ty + j * 8) * S_ + s0 + tx] = t[tx][ty + j * 8];
}

// ---------------------------------------------------------------------------
// MFMA GEMM NT. 128x128 tile, BK=64, 256 thr (4 waves 2x2).
// MODE 1: Wo (bias+resid, out fp32)  MODE 2: FFN1 (LeakyReLU, out bf16)
// MODE 3: FFN2 (bias, out bf16)
// ---------------------------------------------------------------------------
template <int MODE>
__global__ __launch_bounds__(256) void gemm_mfma(
    const bf16* __restrict__ A, const bf16* __restrict__ Bt,
    const float* __restrict__ bias, const float* __restrict__ resid,
    void* __restrict__ Cout, int N, int K,
    const int* __restrict__ ebase, const int* __restrict__ ecnt) {
  __shared__ bf16 Al[128 * 64];
  __shared__ bf16 Bl[128 * 64];
  int tid = threadIdx.x;
  int w = tid >> 6, lane = tid & 63;
  int lg = lane >> 4, li = lane & 15;
  int e = 0;
  size_t arow0;
  if constexpr (MODE >= 2) {
    e = blockIdx.z;
    int r0 = blockIdx.y * 128;
    if (r0 >= ecnt[e]) return;
    arow0 = (size_t)(ebase[e] + r0);
  } else {
    arow0 = (size_t)blockIdx.y * 128;
  }
  int n0 = blockIdx.x * 128;
  const bf16* Bexp = Bt + (size_t)e * N * K;

  int rowA[4], scA[4];
#pragma unroll
  for (int j = 0; j < 4; j++) {
    int o = w * 4096 + j * 1024 + lane * 16;
    rowA[j] = o >> 7;
    scA[j] = ((o >> 4) & 7) ^ (rowA[j] & 7);
  }
  int wm = w >> 1, wn = w & 1;
  f32x4 acc[4][4] = {};

  for (int k0 = 0; k0 < K; k0 += 64) {
#pragma unroll
    for (int j = 0; j < 4; j++) {
      int o = w * 4096 + j * 1024 + lane * 16;
      gload16(A + (arow0 + rowA[j]) * (size_t)K + k0 + scA[j] * 8, (char*)Al + o);
      gload16(Bexp + (size_t)(n0 + rowA[j]) * K + k0 + scA[j] * 8, (char*)Bl + o);
    }
    __syncthreads();
#pragma unroll
    for (int ks = 0; ks < 2; ks++) {
      bf16x8 af[4], bfr[4];
#pragma unroll
      for (int mi = 0; mi < 4; mi++) {
        int row = wm * 64 + mi * 16 + li;
        int cb = (lg * 16 + ks * 64) ^ ((row & 7) << 4);
        af[mi] = *(const bf16x8*)((char*)Al + row * 128 + cb);
      }
#pragma unroll
      for (int ni = 0; ni < 4; ni++) {
        int row = wn * 64 + ni * 16 + li;
        int cb = (lg * 16 + ks * 64) ^ ((row & 7) << 4);
        bfr[ni] = *(const bf16x8*)((char*)Bl + row * 128 + cb);
      }
#pragma unroll
      for (int mi = 0; mi < 4; mi++)
#pragma unroll
        for (int ni = 0; ni < 4; ni++)
          acc[mi][ni] = MFMA16(af[mi], bfr[ni], acc[mi][ni]);
    }
    __syncthreads();
  }

#pragma unroll
  for (int mi = 0; mi < 4; mi++) {
#pragma unroll
    for (int ni = 0; ni < 4; ni++) {
#pragma unroll
      for (int r = 0; r < 4; r++) {
        size_t m = arow0 + wm * 64 + mi * 16 + lg * 4 + r;
        int c = n0 + wn * 64 + ni * 16 + li;
        float v = acc[mi][ni][r];
        if constexpr (MODE == 1) {
          v += bias[c] + resid[m * (size_t)N + c];
          ((float*)Cout)[m * (size_t)N + c] = v;
        } else if constexpr (MODE == 2) {
          if (c < HID_) {
            v += bias[e * HID_ + c];
            v = (v > 0.f) ? v : 0.01f * v;
            ((bf16*)Cout)[m * (size_t)HIDP_ + c] = __float2bfloat16(v);
          } else {
            ((bf16*)Cout)[m * (size_t)HIDP_ + c] = __float2bfloat16(0.f);
          }
        } else {
          v += bias[e * D_ + c];
          ((bf16*)Cout)[m * (size_t)N + c] = __float2bfloat16(v);
        }
      }
    }
  }
}

// ---------------------------------------------------------------------------
// Split-3 high-precision GEMM: C fp32 = A*Bt^T via 6 bf16 MFMA products.
// Full QKV projection (N=1536).
// ---------------------------------------------------------------------------
__global__ __launch_bounds__(256) void gemm_split3(
    const bf16* __restrict__ Ah, const bf16* __restrict__ Am, const bf16* __restrict__ Al_,
    const bf16* __restrict__ Bh, const bf16* __restrict__ Bm, const bf16* __restrict__ Bl_,
    const float* __restrict__ bias, float* __restrict__ C, int N, int K) {
  __shared__ bf16 Ls[6][128 * 32];
  const bf16* Ap[3] = {Ah, Am, Al_};
  const bf16* Bp[3] = {Bh, Bm, Bl_};
  int tid = threadIdx.x;
  int w = tid >> 6, lane = tid & 63;
  int lg = lane >> 4, li = lane & 15;
  size_t m0 = (size_t)blockIdx.y * 128;
  int n0 = blockIdx.x * 128;
  int wm = w >> 1, wn = w & 1;
  f32x4 acc[4][4] = {};

  for (int k0 = 0; k0 < K; k0 += 32) {
#pragma unroll
    for (int p = 0; p < 3; p++) {
#pragma unroll
      for (int j = 0; j < 2; j++) {
        int o = w * 2048 + j * 1024 + lane * 16;
        int row = o >> 6;
        int sc = ((o >> 4) & 3) ^ (row & 3);
        gload16(Ap[p] + (m0 + row) * (size_t)K + k0 + sc * 8, (char*)Ls[p] + o);
        gload16(Bp[p] + (size_t)(n0 + row) * K + k0 + sc * 8, (char*)Ls[3 + p] + o);
      }
    }
    __syncthreads();
    bf16x8 af[3][4], bfv[3][4];
#pragma unroll
    for (int p = 0; p < 3; p++) {
#pragma unroll
      for (int mi = 0; mi < 4; mi++) {
        int row = wm * 64 + mi * 16 + li;
        int cb = (lg * 16) ^ ((row & 3) << 4);
        af[p][mi] = *(const bf16x8*)((char*)Ls[p] + row * 64 + cb);
      }
#pragma unroll
      for (int ni = 0; ni < 4; ni++) {
        int row = wn * 64 + ni * 16 + li;
        int cb = (lg * 16) ^ ((row & 3) << 4);
        bfv[p][ni] = *(const bf16x8*)((char*)Ls[3 + p] + row * 64 + cb);
      }
    }
#pragma unroll
    for (int mi = 0; mi < 4; mi++)
#pragma unroll
      for (int ni = 0; ni < 4; ni++) {
        acc[mi][ni] = MFMA16(af[0][mi], bfv[0][ni], acc[mi][ni]);
        acc[mi][ni] = MFMA16(af[0][mi], bfv[1][ni], acc[mi][ni]);
        acc[mi][ni] = MFMA16(af[1][mi], bfv[0][ni], acc[mi][ni]);
        acc[mi][ni] = MFMA16(af[1][mi], bfv[1][ni], acc[mi][ni]);
        acc[mi][ni] = MFMA16(af[0][mi], bfv[2][ni], acc[mi][ni]);
        acc[mi][ni] = MFMA16(af[2][mi], bfv[0][ni], acc[mi][ni]);
      }
    __syncthreads();
  }
#pragma unroll
  for (int mi = 0; mi < 4; mi++)
#pragma unroll
    for (int ni = 0; ni < 4; ni++)
#pragma unroll
      for (int r = 0; r < 4; r++) {
        size_t m = m0 + wm * 64 + mi * 16 + lg * 4 + r;
        int c = n0 + wn * 64 + ni * 16 + li;
        C[m * (size_t)N + c] = acc[mi][ni][r] + bias[c];
      }
}

// ---------------------------------------------------------------------------
// MFMA flash attention (fast value path). 512 thr = 8 waves, 128 q rows.
// ---------------------------------------------------------------------------
__global__ __launch_bounds__(512) void attn_mfma(
    const bf16* __restrict__ qkv, const bf16* __restrict__ vT,
    bf16* __restrict__ attnb) {
  __shared__ bf16 Kl[128 * 64];
  __shared__ bf16 Vtl[64 * 128];
  __shared__ bf16 Pl[8][16 * 128];
  int b = blockIdx.z, h = blockIdx.y, q0 = blockIdx.x * 128;
  int tid = threadIdx.x, w = tid >> 6, lane = tid & 63;
  int lg = lane >> 4, qi = lane & 15;

  bf16x8 qf[2];
  const bf16* qrow =
      qkv + ((size_t)(b * S_ + q0 + w * 16 + qi)) * (3 * D_) + h * DH_ + lg * 8;
  qf[0] = *(const bf16x8*)(qrow);
  qf[1] = *(const bf16x8*)(qrow + 32);

  f32x4 oacc[4] = {};
  float mrun = -1e30f, lrun = 0.f;
  const bf16* Kbase = qkv + (size_t)b * S_ * (3 * D_) + D_ + h * DH_;
  const bf16* Vbase = vT + (size_t)(b * H_ + h) * DH_ * S_;
  char* pw = (char*)&Pl[w][0];

  for (int kt = 0; kt < S_ / 128; kt++) {
#pragma unroll
    for (int j = 0; j < 2; j++) {
      int o = w * 2048 + j * 1024 + lane * 16;
      int row = o >> 7;
      int sc = ((o >> 4) & 7) ^ (row & 7);
      gload16(Kbase + (size_t)(kt * 128 + row) * (3 * D_) + sc * 8, (char*)Kl + o);
    }
#pragma unroll
    for (int j = 0; j < 2; j++) {
      int o = w * 2048 + j * 1024 + lane * 16;
      int row = o >> 8;
      int sc = ((o >> 4) & 15) ^ (row & 7);
      gload16(Vbase + (size_t)row * S_ + kt * 128 + sc * 8, (char*)Vtl + o);
    }
    __syncthreads();

    f32x4 sacc[8];
#pragma unroll
    for (int nb = 0; nb < 8; nb++) { f32x4 z = {0.f, 0.f, 0.f, 0.f}; sacc[nb] = z; }
#pragma unroll
    for (int ks = 0; ks < 2; ks++) {
#pragma unroll
      for (int nb = 0; nb < 8; nb++) {
        int row = nb * 16 + qi;
        int cb = (lg * 16 + ks * 64) ^ ((row & 7) << 4);
        bf16x8 kf = *(const bf16x8*)((char*)Kl + row * 128 + cb);
        sacc[nb] = MFMA16(kf, qf[ks], sacc[nb]);
      }
    }
    float p[32];
    float tmax = -1e30f;
#pragma unroll
    for (int nb = 0; nb < 8; nb++)
#pragma unroll
      for (int r = 0; r < 4; r++) {
        float v = sacc[nb][r] * 0.125f;
        p[nb * 4 + r] = v;
        tmax = fmaxf(tmax, v);
      }
    tmax = fmaxf(tmax, __shfl_xor(tmax, 16));
    tmax = fmaxf(tmax, __shfl_xor(tmax, 32));
    float mnew = fmaxf(mrun, tmax);
    float fsc = __expf(mrun - mnew);
    float psum = 0.f;
#pragma unroll
    for (int i = 0; i < 32; i++) { p[i] = __expf(p[i] - mnew); psum += p[i]; }
    psum += __shfl_xor(psum, 16);
    psum += __shfl_xor(psum, 32);
    lrun = lrun * fsc + psum;
    mrun = mnew;
#pragma unroll
    for (int db = 0; db < 4; db++)
#pragma unroll
      for (int r = 0; r < 4; r++) oacc[db][r] *= fsc;
#pragma unroll
    for (int nb = 0; nb < 8; nb++)
#pragma unroll
      for (int rp = 0; rp < 2; rp++) {
        unsigned pk = bf16pk(p[nb * 4 + rp * 2], p[nb * 4 + rp * 2 + 1]);
        int key = 4 * lg + 2 * rp + 16 * nb;
        int addr = (qi * 256 + key * 2) ^ ((qi & 7) << 4);
        *(unsigned*)(pw + addr) = pk;
      }
#pragma unroll
    for (int ks2 = 0; ks2 < 4; ks2++) {
      int cbp = (qi * 256) + ((lg * 16 + ks2 * 64) ^ ((qi & 7) << 4));
      bf16x8 pf = *(const bf16x8*)(pw + cbp);
#pragma unroll
      for (int db = 0; db < 4; db++) {
        int row = db * 16 + qi;
        int cb = (lg * 16 + ks2 * 64) ^ ((row & 7) << 4);
        bf16x8 vf = *(const bf16x8*)((char*)Vtl + row * 256 + cb);
        oacc[db] = MFMA16(vf, pf, oacc[db]);
      }
    }
    __syncthreads();
  }

  float inv = 1.f / lrun;
  char* ow = (char*)Kl + w * 16 * 128;
#pragma unroll
  for (int db = 0; db < 4; db++)
#pragma unroll
    for (int rp = 0; rp < 2; rp++) {
      int d = db * 16 + lg * 4 + rp * 2;
      unsigned pk = bf16pk(oacc[db][rp * 2] * inv, oacc[db][rp * 2 + 1] * inv);
      int addr = (qi * 128 + d * 2) ^ ((qi & 7) << 4);
      *(unsigned*)(ow + addr) = pk;
    }
#pragma unroll
  for (int j = 0; j < 2; j++) {
    int o = j * 1024 + lane * 16;
    int q = o >> 7;
    int c16 = (o >> 4) & 7;
    int sc = c16 ^ (q & 7);
    bf16x8 vv = *(const bf16x8*)(ow + q * 128 + sc * 16);
    *(bf16x8*)(attnb + ((size_t)(b * S_ + q0 + w * 16 + q)) * D_ + h * DH_ + c16 * 8) = vv;
  }
}

// ---------------------------------------------------------------------------
// ksplit: k-part of qkv32 -> head-major split-3 bf16 [b*8+h][2048][64]
// ---------------------------------------------------------------------------
__global__ __launch_bounds__(256) void ksplit(const float* __restrict__ qkv32,
    unsigned short* __restrict__ kh, unsigned short* __restrict__ km,
    unsigned short* __restrict__ kl) {
  int gid = blockIdx.x * 256 + threadIdx.x;   // TOK*512/4 threads
  int idx4 = gid * 4;
  int t = idx4 >> 9, c = idx4 & 511;
  int h = c >> 6, d = c & 63;
  int b = t >> 11, s = t & 2047;
  float4 v = *(const float4*)(qkv32 + (size_t)t * 1536 + 512 + c);
  float a[4] = {v.x, v.y, v.z, v.w};
  ushort4 hh, mm, ll;
  unsigned short* hp = (unsigned short*)&hh;
  unsigned short* mp = (unsigned short*)&mm;
  unsigned short* lp = (unsigned short*)&ll;
#pragma unroll
  for (int j = 0; j < 4; j++) {
    float fh, fm, fl;
    hp[j] = bf16rne(a[j], fh);
    float r = a[j] - fh;
    mp[j] = bf16rne(r, fm);
    float r2 = r - fm;
    lp[j] = bf16rne(r2, fl);
  }
  size_t o = (((size_t)(b * 8 + h) * S_ + s) * 64 + d);
  *(ushort4*)(kh + o) = hh;
  *(ushort4*)(km + o) = mm;
  *(ushort4*)(kl + o) = ll;
}

// ---------------------------------------------------------------------------
// Wg2[d][e] = sum_n Wo[n][d] * Wg[n][e]
// ---------------------------------------------------------------------------
__global__ __launch_bounds__(256) void wg2_kernel(const float* __restrict__ Wo,
                                                  const float* __restrict__ Wg,
                                                  float* __restrict__ Wg2) {
  int gid = blockIdx.x * 256 + threadIdx.x;   // 4096
  int d = gid >> 3, e = gid & 7;
  float acc = 0.f;
  for (int n = 0; n < D_; n++) acc += Wo[(size_t)n * D_ + d] * Wg[n * E_ + e];
  Wg2[d * E_ + e] = acc;
}

// ---------------------------------------------------------------------------
// U[b*8+h][s][e] = sum_d V32[b,s,h*64+d] * Wg2[h*64+d][e]
// ---------------------------------------------------------------------------
__global__ __launch_bounds__(256) void uproj(const float* __restrict__ qkv32,
                                             const float* __restrict__ Wg2,
                                             float* __restrict__ U) {
  int gid = blockIdx.x * 256 + threadIdx.x;   // B*H*S*8
  int e = gid & 7;
  size_t row = (size_t)(gid >> 3);            // (b*8+h)*2048+s
  int s = row & 2047;
  int h = (row >> 11) & 7;
  int b = (int)(row >> 14);
  const float* vsrc = qkv32 + ((size_t)(b * S_ + s)) * 1536 + 1024 + h * 64;
  const float* wsrc = Wg2 + h * 64 * E_ + e;
  float acc = 0.f;
#pragma unroll 8
  for (int d = 0; d < 64; d++) acc += vsrc[d] * wsrc[d * E_];
  U[row * 8 + e] = acc;
}

// ---------------------------------------------------------------------------
// xwg: logits init = (x[t]+bo) @ Wg   (the residual+bias part of logits)
// ---------------------------------------------------------------------------
__global__ __launch_bounds__(256) void xwg_kernel(const float* __restrict__ x,
                                                  const float* __restrict__ bo,
                                                  const float* __restrict__ Wg,
                                                  float* __restrict__ logits) {
  int tid = threadIdx.x;
  int tl = tid >> 3, j = tid & 7;
  int t = blockIdx.x * 32 + tl;
  const float* xr = x + (size_t)t * D_;
  float part[8] = {0, 0, 0, 0, 0, 0, 0, 0};
  for (int d = j; d < D_; d += 8) {
    float xv = xr[d] + bo[d];
    const float* wg = Wg + d * E_;
#pragma unroll
    for (int e = 0; e < 8; e++) part[e] += xv * wg[e];
  }
#pragma unroll
  for (int off = 1; off < 8; off <<= 1)
#pragma unroll
    for (int e = 0; e < 8; e++) part[e] += __shfl_xor(part[e], off);
  if (j == 0) {
#pragma unroll
    for (int e = 0; e < 8; e++) logits[(size_t)t * 8 + e] = part[e];
  }
}

// ---------------------------------------------------------------------------
// routing_attn: accurate logit contributions per head.
// Scores via split-3 bf16 MFMA (6 products); softmax fp32; P @ U (8-wide).
// Grid (S/128, H, B), 512 thr. part[(b*8+h)*S + s][e] = (sum p*U)/l
// ---------------------------------------------------------------------------
__global__ __launch_bounds__(512) void routing_attn(
    const float* __restrict__ qkv32,
    const bf16* __restrict__ kh, const bf16* __restrict__ km,
    const bf16* __restrict__ kl,
    const float* __restrict__ U, float* __restrict__ part) {
  __shared__ bf16 Ks0[128 * 64];
  __shared__ bf16 Ks1[128 * 64];
  __shared__ bf16 Ks2[128 * 64];
  __shared__ float Us[128 * 12];
  int b = blockIdx.z, h = blockIdx.y, q0 = blockIdx.x * 128;
  int bh = b * 8 + h;
  int tid = threadIdx.x, w = tid >> 6, lane = tid & 63;
  int lg = lane >> 4, qi = lane & 15;

  // q fragments, split-3 in-register
  const float* qsrc = qkv32 + (size_t)(b * S_ + q0 + w * 16 + qi) * 1536 + h * 64 + lg * 8;
  bf16x8 qh[2], qm[2], ql[2];
#pragma unroll
  for (int ks = 0; ks < 2; ks++) {
#pragma unroll
    for (int i = 0; i < 8; i++) {
      float xv = qsrc[ks * 32 + i];
      float fh, fm, fl;
      unsigned short ah = bf16rne(xv, fh);
      float r = xv - fh;
      unsigned short am = bf16rne(r, fm);
      float r2 = r - fm;
      unsigned short al = bf16rne(r2, fl);
      ((unsigned short*)&qh[ks])[i] = ah;
      ((unsigned short*)&qm[ks])[i] = am;
      ((unsigned short*)&ql[ks])[i] = al;
    }
  }

  float lacc[8] = {0, 0, 0, 0, 0, 0, 0, 0};
  float mrun = -1e30f, lrun = 0.f;

  for (int kt = 0; kt < S_ / 128; kt++) {
#pragma unroll
    for (int j = 0; j < 2; j++) {
      int o = w * 2048 + j * 1024 + lane * 16;
      int row = o >> 7;
      int sc = ((o >> 4) & 7) ^ (row & 7);
      size_t src = ((size_t)bh * S_ + kt * 128 + row) * 64 + sc * 8;
      gload16(kh + src, (char*)Ks0 + o);
      gload16(km + src, (char*)Ks1 + o);
      gload16(kl + src, (char*)Ks2 + o);
    }
    if (tid < 256) {
      int r = tid >> 1, hf = tid & 1;
      float4 uv = *(const float4*)(U + ((size_t)bh * S_ + kt * 128 + r) * 8 + hf * 4);
      *(float4*)(Us + r * 12 + hf * 4) = uv;
    }
    __syncthreads();

    f32x4 sacc[8];
#pragma unroll
    for (int nb = 0; nb < 8; nb++) { f32x4 z = {0.f, 0.f, 0.f, 0.f}; sacc[nb] = z; }
#pragma unroll
    for (int ks = 0; ks < 2; ks++) {
#pragma unroll
      for (int nb = 0; nb < 8; nb++) {
        int row = nb * 16 + qi;
        int cb = (lg * 16 + ks * 64) ^ ((row & 7) << 4);
        bf16x8 k0 = *(const bf16x8*)((char*)Ks0 + row * 128 + cb);
        bf16x8 k1 = *(const bf16x8*)((char*)Ks1 + row * 128 + cb);
        bf16x8 k2 = *(const bf16x8*)((char*)Ks2 + row * 128 + cb);
        sacc[nb] = MFMA16(k0, qh[ks], sacc[nb]);
        sacc[nb] = MFMA16(k0, qm[ks], sacc[nb]);
        sacc[nb] = MFMA16(k1, qh[ks], sacc[nb]);
        sacc[nb] = MFMA16(k1, qm[ks], sacc[nb]);
        sacc[nb] = MFMA16(k2, qh[ks], sacc[nb]);
        sacc[nb] = MFMA16(k0, ql[ks], sacc[nb]);
      }
    }
    // online softmax (in-place over sacc)
    float tmax = -1e30f;
#pragma unroll
    for (int nb = 0; nb < 8; nb++)
#pragma unroll
      for (int r = 0; r < 4; r++) {
        float v = sacc[nb][r] * 0.125f;
        sacc[nb][r] = v;
        tmax = fmaxf(tmax, v);
      }
    tmax = fmaxf(tmax, __shfl_xor(tmax, 16));
    tmax = fmaxf(tmax, __shfl_xor(tmax, 32));
    float mnew = fmaxf(mrun, tmax);
    float fsc = __expf(mrun - mnew);
    float psum = 0.f;
#pragma unroll
    for (int nb = 0; nb < 8; nb++)
#pragma unroll
      for (int r = 0; r < 4; r++) {
        float pv = __expf(sacc[nb][r] - mnew);
        sacc[nb][r] = pv;
        psum += pv;
      }
    psum += __shfl_xor(psum, 16);
    psum += __shfl_xor(psum, 32);
    lrun = lrun * fsc + psum;
    mrun = mnew;
#pragma unroll
    for (int e = 0; e < 8; e++) lacc[e] *= fsc;
#pragma unroll
    for (int nb = 0; nb < 8; nb++)
#pragma unroll
      for (int r = 0; r < 4; r++) {
        float pv = sacc[nb][r];
        int key = 4 * lg + r + 16 * nb;
        f32x4 ua = *(const f32x4*)(Us + key * 12);
        f32x4 ub = *(const f32x4*)(Us + key * 12 + 4);
        lacc[0] += pv * ua[0]; lacc[1] += pv * ua[1];
        lacc[2] += pv * ua[2]; lacc[3] += pv * ua[3];
        lacc[4] += pv * ub[0]; lacc[5] += pv * ub[1];
        lacc[6] += pv * ub[2]; lacc[7] += pv * ub[3];
      }
    __syncthreads();
  }
#pragma unroll
  for (int e = 0; e < 8; e++) {
    lacc[e] += __shfl_xor(lacc[e], 16);
    lacc[e] += __shfl_xor(lacc[e], 32);
  }
  if (lg == 0) {
    float inv = 1.f / lrun;
    float* dst = part + ((size_t)bh * S_ + q0 + w * 16 + qi) * 8;
#pragma unroll
    for (int e = 0; e < 8; e++) dst[e] = lacc[e] * inv;
  }
}

// ---------------------------------------------------------------------------
// reduce_gate: final logits = xwg + sum_h part; decisions + aux stats.
// ---------------------------------------------------------------------------
__global__ __launch_bounds__(256) void reduce_gate(
    const float* __restrict__ xwg, const float* __restrict__ part,
    int* __restrict__ e1a, int* __restrict__ e2a,
    float* __restrict__ g1a, float* __restrict__ g2a, int* __restrict__ use2a,
    float* __restrict__ dacc) {
  int t = blockIdx.x * 256 + threadIdx.x;
  int b = t >> 11, s = t & 2047;
  float lg[8];
#pragma unroll
  for (int e = 0; e < 8; e++) lg[e] = xwg[(size_t)t * 8 + e];
  for (int h = 0; h < 8; h++) {
    const float* pp = part + ((size_t)(b * 8 + h) * S_ + s) * 8;
#pragma unroll
    for (int e = 0; e < 8; e++) lg[e] += pp[e];
  }
  float mx = lg[0];
#pragma unroll
  for (int e = 1; e < 8; e++) mx = fmaxf(mx, lg[e]);
  float p[8], se = 0.f;
#pragma unroll
  for (int e = 0; e < 8; e++) { p[e] = expf(lg[e] - mx); se += p[e]; }
  float inv = 1.f / se;
#pragma unroll
  for (int e = 0; e < 8; e++) p[e] *= inv;
  float lse = logf(se) + mx;
  int a1 = 0; float m1 = p[0];
#pragma unroll
  for (int e = 1; e < 8; e++) if (p[e] > m1) { m1 = p[e]; a1 = e; }
  int a2 = -1; float m2 = -1.f;
#pragma unroll
  for (int e = 0; e < 8; e++) if (e != a1 && p[e] > m2) { m2 = p[e]; a2 = e; }
  e1a[t] = a1; e2a[t] = a2; g1a[t] = m1; g2a[t] = m2;
  use2a[t] = (m2 > 0.2f) ? 1 : 0;
  // stats
  float z = lse * lse;
  float pr[8];
#pragma unroll
  for (int e = 0; e < 8; e++) pr[e] = p[e];
#pragma unroll
  for (int off = 1; off < 64; off <<= 1) {
#pragma unroll
    for (int e = 0; e < 8; e++) pr[e] += __shfl_xor(pr[e], off);
    z += __shfl_xor(z, off);
  }
  float dcnt[8];
#pragma unroll
  for (int e = 0; e < 8; e++) dcnt[e] = (float)__popcll(__ballot(a1 == e));
  if ((threadIdx.x & 63) == 0) {
#pragma unroll
    for (int e = 0; e < 8; e++) {
      atomicAdd(&dacc[e], dcnt[e]);
      atomicAdd(&dacc[8 + e], pr[e]);
    }
    atomicAdd(&dacc[16], z);
  }
}

// ---------------------------------------------------------------------------
// Capacity scan (exact cumsum order).
// ---------------------------------------------------------------------------
__global__ void scan_kernel(const int* __restrict__ e1a, const int* __restrict__ e2a,
                            const int* __restrict__ use2a,
                            int* __restrict__ posArr, int* __restrict__ kept_be) {
  int b = blockIdx.x;
  int lane = threadIdx.x;
  int cnt[8] = {0, 0, 0, 0, 0, 0, 0, 0};
  unsigned long long below = (1ull << lane) - 1ull;
  for (int it = 0; it < (2 * S_) / 64; it++) {
    int i = it * 64 + lane;
    int s = i & (S_ - 1);
    int t = b * S_ + s;
    int e, a;
    if (i < S_) { e = e1a[t]; a = 1; }
    else        { e = e2a[t]; a = use2a[t]; }
    int pos = -1;
#pragma unroll
    for (int ee = 0; ee < 8; ee++) {
      unsigned long long mask = __ballot(a && (e == ee));
      if (a && e == ee) pos = cnt[ee] + __popcll(mask & below);
      cnt[ee] += __popcll(mask);
    }
    posArr[b * (2 * S_) + i] = (a && pos < CAP_) ? pos : -1;
  }
  if (lane == 0)
    for (int ee = 0; ee < 8; ee++) kept_be[b * 8 + ee] = min(cnt[ee], CAP_);
}

// ---------------------------------------------------------------------------
// Meta: 128-aligned per-expert bases + aux-loss scalars.
// ---------------------------------------------------------------------------
__global__ void finalize_meta(const int* __restrict__ kept_be,
                              int* __restrict__ ebase, int* __restrict__ bbase,
                              int* __restrict__ ecnt,
                              const float* __restrict__ dacc, float* __restrict__ outs) {
  if (threadIdx.x == 0 && blockIdx.x == 0) {
    int base = 0;
    for (int e = 0; e < 8; e++) {
      int tot = 0;
      for (int b = 0; b < 4; b++) { bbase[b * 8 + e] = tot; tot += kept_be[b * 8 + e]; }
      ecnt[e] = tot;
      ebase[e] = base;
      base += (tot + 127) & ~127;
    }
    float bal = 0.f;
    for (int e = 0; e < 8; e++) bal += (dacc[e] / (float)TOK_) * (dacc[8 + e] / (float)TOK_);
    bal *= (float)E_;
    float z = dacc[16] / (float)TOK_;
    outs[0] = 0.01f * bal + 0.001f * z;
    outs[1] = bal;
    outs[2] = z;
  }
}

// ---------------------------------------------------------------------------
// Scatter: compacted row lists + per-token combine info.
// ---------------------------------------------------------------------------
__global__ __launch_bounds__(256) void scatter_kernel(
    const int* __restrict__ posArr, const int* __restrict__ e1a, const int* __restrict__ e2a,
    const float* __restrict__ g1a, const float* __restrict__ g2a,
    const int* __restrict__ ebase, const int* __restrict__ bbase,
    int* __restrict__ rowtok, int* __restrict__ rowexp,
    int* __restrict__ tokidx, float* __restrict__ tokw) {
  int gi = blockIdx.x * 256 + threadIdx.x;
  int b = gi >> 12, i = gi & 4095;
  int k = i >> 11, s = i & (S_ - 1);
  int t = b * S_ + s;
  int pos = posArr[gi];
  int idx = -1; float w = 0.f;
  if (pos >= 0) {
    int e = k ? e2a[t] : e1a[t];
    idx = ebase[e] + bbase[b * 8 + e] + pos;
    rowtok[idx] = t;
    rowexp[idx] = e;
    w = k ? g2a[t] : g1a[t];
  }
  tokidx[k * TOK_ + t] = idx;
  tokw[k * TOK_ + t] = w;
}

// ---------------------------------------------------------------------------
// LayerNorm per compacted row -> bf16.
// ---------------------------------------------------------------------------
__global__ __launch_bounds__(256) void ln_kernel(
    const float* __restrict__ o2, const int* __restrict__ rowtok,
    const int* __restrict__ rowexp, const float* __restrict__ ln_g,
    const float* __restrict__ ln_b, bf16* __restrict__ xn) {
  int row = blockIdx.x * 4 + (threadIdx.x >> 6);
  int lane = threadIdx.x & 63;
  int tok = rowtok[row];
  if (tok < 0) return;
  int e = rowexp[row];
  const float* xr = o2 + (size_t)tok * D_;
  float v[8], sum = 0.f, sq = 0.f;
#pragma unroll
  for (int j = 0; j < 8; j++) { v[j] = xr[lane * 8 + j]; sum += v[j]; sq += v[j] * v[j]; }
#pragma unroll
  for (int off = 1; off < 64; off <<= 1) { sum += __shfl_xor(sum, off); sq += __shfl_xor(sq, off); }
  float mu = sum / (float)D_;
  float var = sq / (float)D_ - mu * mu;
  float inv = rsqrtf(var + 1e-5f);
  bf16* xo = xn + (size_t)row * D_;
#pragma unroll
  for (int j = 0; j < 8; j++) {
    int d = lane * 8 + j;
    xo[d] = __float2bfloat16((v[j] - mu) * inv * ln_g[e * D_ + d] + ln_b[e * D_ + d]);
  }
}

// ---------------------------------------------------------------------------
// Combine: out = o2 + w1*y[idx1] + w2*y[idx2]   (y bf16)
// ---------------------------------------------------------------------------
__global__ __launch_bounds__(256) void combine_kernel(
    const float* __restrict__ o2, const bf16* __restrict__ y,
    const int* __restrict__ tokidx, const float* __restrict__ tokw,
    float* __restrict__ out) {
  size_t gi = (size_t)blockIdx.x * 256 + threadIdx.x;
  int t = (int)(gi >> 9);
  int d = (int)(gi & (D_ - 1));
  float v = o2[gi];
  int i1 = tokidx[t], i2 = tokidx[TOK_ + t];
  if (i1 >= 0) v += tokw[t] * __bfloat162float(y[(size_t)i1 * D_ + d]);
  if (i2 >= 0) v += tokw[TOK_ + t] * __bfloat162float(y[(size_t)i2 * D_ + d]);
  out[gi] = v;
}

// ---------------------------------------------------------------------------
extern "C" void kernel_launch(void* const* d_in, const int* in_sizes, int n_in,
                              void* d_out, int out_size, void* d_ws, size_t ws_size,
                              hipStream_t stream) {
  const float* x    = (const float*)d_in[0];
  const float* Wqkv = (const float*)d_in[1];
  const float* bqkv = (const float*)d_in[2];
  const float* Wo   = (const float*)d_in[3];
  const float* bo   = (const float*)d_in[4];
  const float* Wg   = (const float*)d_in[5];
  const float* ln_g = (const float*)d_in[6];
  const float* ln_b = (const float*)d_in[7];
  const float* W1   = (const float*)d_in[8];
  const float* b1   = (const float*)d_in[9];
  const float* W2   = (const float*)d_in[10];
  const float* b2   = (const float*)d_in[11];
  float* out = (float*)d_out;

  char* ws = (char*)d_ws;
  size_t off = 0;
  auto alloc = [&](size_t bytes) -> void* {
    void* p = ws + off;
    off = (off + bytes + 255) & ~(size_t)255;
    return p;
  };
  float* qkv32 = (float*)alloc((size_t)TOK_ * 1536 * 4);   // 50.3 MB
  bf16* qkvb   = (bf16*)alloc((size_t)TOK_ * 1536 * 2);    // 25.2 MB
  bf16* vT     = (bf16*)alloc((size_t)B_ * H_ * DH_ * S_ * 2);
  bf16* attnb  = (bf16*)alloc((size_t)TOK_ * D_ * 2);
  float* o2    = (float*)alloc((size_t)TOK_ * D_ * 4);
  bf16* xh     = (bf16*)alloc((size_t)TOK_ * D_ * 2);
  bf16* xm     = (bf16*)alloc((size_t)TOK_ * D_ * 2);
  bf16* xl     = (bf16*)alloc((size_t)TOK_ * D_ * 2);
  bf16* Wqh    = (bf16*)alloc((size_t)1536 * D_ * 2);
  bf16* Wqm    = (bf16*)alloc((size_t)1536 * D_ * 2);
  bf16* Wql    = (bf16*)alloc((size_t)1536 * D_ * 2);
  bf16* Wob    = (bf16*)alloc((size_t)D_ * D_ * 2);
  bf16* W1t    = (bf16*)alloc((size_t)E_ * HIDP_ * D_ * 2);
  bf16* W2t    = (bf16*)alloc((size_t)E_ * D_ * HIDP_ * 2);
  bf16* xn     = (bf16*)alloc((size_t)RMAX_ * D_ * 2);
  bf16* hbuf   = (bf16*)alloc((size_t)RMAX_ * HIDP_ * 2);
  bf16* ybuf   = (bf16*)alloc((size_t)RMAX_ * D_ * 2);
  float* Wg2   = (float*)alloc(D_ * E_ * 4);
  float* U     = (float*)alloc((size_t)B_ * H_ * S_ * 8 * 4);   // 2.1 MB
  float* logits= (float*)alloc((size_t)TOK_ * 8 * 4);
  float* part  = (float*)alloc((size_t)B_ * H_ * S_ * 8 * 4);   // 2.1 MB
  int*   e1a   = (int*)alloc(TOK_ * 4);
  int*   e2a   = (int*)alloc(TOK_ * 4);
  int*   use2a = (int*)alloc(TOK_ * 4);
  float* g1a   = (float*)alloc(TOK_ * 4);
  float* g2a   = (float*)alloc(TOK_ * 4);
  int*   posArr  = (int*)alloc(NASS_ * 4);
  int*   kept_be = (int*)alloc(32 * 4);
  int*   ebase   = (int*)alloc(8 * 4);
  int*   bbase   = (int*)alloc(32 * 4);
  int*   ecnt    = (int*)alloc(8 * 4);
  int*   rowtok  = (int*)alloc(RMAX_ * 4);
  int*   rowexp  = (int*)alloc(RMAX_ * 4);
  int*   tokidx  = (int*)alloc(NASS_ * 4);
  float* tokw    = (float*)alloc(NASS_ * 4);
  float* dacc    = (float*)alloc(32 * 4);
  // kh/km/kl alias xh/xm/xl: same size (TOK_*D_*2), disjoint lifetime
  // (xh/xm/xl dead after gemm_split3; ksplit runs after it).
  bf16* kh = xh;
  bf16* km = xm;
  bf16* kl = xl;

  hipMemsetAsync(dacc, 0, 32 * 4, stream);
  hipMemsetAsync(rowtok, 0xFF, RMAX_ * 4, stream);

  // conversions / splits
  split3v<<<TOK_ * D_ / 4 / 256, 256, 0, stream>>>(x, (unsigned short*)xh,
                                                   (unsigned short*)xm,
                                                   (unsigned short*)xl, TOK_ * D_);
  split3v<<<1536 * D_ / 4 / 256, 256, 0, stream>>>(Wqkv, (unsigned short*)Wqh,
                                                   (unsigned short*)Wqm,
                                                   (unsigned short*)Wql, 1536 * D_);
  cvt_bf16<<<D_ * D_ / 4 / 256, 256, 0, stream>>>(Wo, Wob, D_ * D_);
  transpose_w1<<<dim3(44, 16, 8), 256, 0, stream>>>(W1, W1t);
  transpose_w2<<<dim3(16, 44, 8), 256, 0, stream>>>(W2, W2t);

  // accurate full QKV (fp32, split-3), then bf16 shadow
  gemm_split3<<<dim3(12, 64), 256, 0, stream>>>(xh, xm, xl, Wqh, Wqm, Wql,
                                                bqkv, qkv32, 1536, D_);
  cvt_bf16<<<TOK_ * 1536 / 4 / 256, 256, 0, stream>>>(qkv32, qkvb, TOK_ * 1536);
  // routing-path preparation (kh/km/kl overwrite xh/xm/xl — safe, see alias note)
  ksplit<<<TOK_ * 512 / 4 / 256, 256, 0, stream>>>(qkv32, (unsigned short*)kh,
                                                   (unsigned short*)km,
                                                   (unsigned short*)kl);
  wg2_kernel<<<16, 256, 0, stream>>>(Wo, Wg, Wg2);
  uproj<<<B_ * H_ * S_ * 8 / 256, 256, 0, stream>>>(qkv32, Wg2, U);
  xwg_kernel<<<TOK_ / 32, 256, 0, stream>>>(x, bo, Wg, logits);

  // value path
  transpose_v<<<dim3(64, 2, 32), 256, 0, stream>>>(qkvb, vT);
  attn_mfma<<<dim3(S_ / 128, H_, B_), 512, 0, stream>>>(qkvb, vT, attnb);
  gemm_mfma<1><<<dim3(4, 64), 256, 0, stream>>>(attnb, Wob, bo, x, o2,
                                                D_, D_, nullptr, nullptr);
  // routing path (accurate logits)
  routing_attn<<<dim3(S_ / 128, H_, B_), 512, 0, stream>>>(qkv32, kh, km, kl, U, part);
  reduce_gate<<<TOK_ / 256, 256, 0, stream>>>(logits, part, e1a, e2a, g1a, g2a,
                                              use2a, dacc);
  // dispatch + expert FFN + combine
  scan_kernel<<<B_, 64, 0, stream>>>(e1a, e2a, use2a, posArr, kept_be);
  finalize_meta<<<1, 64, 0, stream>>>(kept_be, ebase, bbase, ecnt, dacc,
                                      out + (size_t)TOK_ * D_);
  scatter_kernel<<<NASS_ / 256, 256, 0, stream>>>(posArr, e1a, e2a, g1a, g2a,
                                                  ebase, bbase, rowtok, rowexp,
                                                  tokidx, tokw);
  ln_kernel<<<RMAX_ / 4, 256, 0, stream>>>(o2, rowtok, rowexp, ln_g, ln_b, xn);
  gemm_mfma<2><<<dim3(HIDP_ / 128, 32, E_), 256, 0, stream>>>(xn, W1t, b1, nullptr, hbuf,
                                                              HIDP_, D_, ebase, ecnt);
  gemm_mfma<3><<<dim3(D_ / 128, 32, E_), 256, 0, stream>>>(hbuf, W2t, b2, nullptr, ybuf,
                                                           D_, HIDP_, ebase, ecnt);
  combine_kernel<<<(TOK_ * D_) / 256, 256, 0, stream>>>(o2, ybuf, tokidx, tokw, out);
}